// Round 6
// baseline (656.309 us; speedup 1.0000x reference)
//
#include <hip/hip_runtime.h>
#include <hip/hip_fp16.h>
#include <math.h>

// Bucketed edge binning (per-tile LDS counting sort -> coalesced bucket
// writes), then SORT-FREE aggregation: per-bucket LDS accumulators with
// ds_add_f32 (padded stride 17 -> conflict-free for random dstLow).
// gemm1 (x@W1, dinv-prescaled) via MFMA f32_16x16x32_f16.
// R1: wave-shuffle scans. R3: quad-split agg (superseded). R5: masked tails
// (superseded). R6: k_sortbucket + csr_src ELIMINATED — aggregation works
// directly on binned[] per bucket with LDS atomic accumulation; deg/dinv
// from a stripped histogram-only kernel (k_hist). Removes ~25 µs of sort +
// 39 MB of csr traffic at the cost of ~5 µs hist + ~4 µs chip-wide ds_add.
#define BSHIFT 8
#define BUCK   256
#define TILE   8192     // edges per scatter workgroup (1024 threads, 8 edges/thread)
#define CAP    12288    // bucket capacity; mean 8184, sigma 90 -> 45 sigma headroom

typedef _Float16 f16x4 __attribute__((ext_vector_type(4)));
typedef _Float16 f16x8 __attribute__((ext_vector_type(8)));
typedef float    f32x4 __attribute__((ext_vector_type(4)));

// ---------------- CSR-free build ----------------

__global__ __launch_bounds__(256) void k_curinit(int* __restrict__ bcursor, int nbuk) {
    int b = blockIdx.x * 256 + threadIdx.x;
    if (b < nbuk) bcursor[b] = b * CAP;
}

// tile scatter with full per-tile LDS counting sort by bucket, so the global
// binned[] writes are lane-consecutive (coalesced bursts per bucket run).
// packed edge = (dst&255)<<17 | src   (src < 2^17)
__global__ __launch_bounds__(1024) void k_binscatter(const int* __restrict__ src,
                                                     const int* __restrict__ dst,
                                                     int* __restrict__ bcursor,
                                                     int* __restrict__ binned, int E, int nbuk) {
    __shared__ int            payload[TILE];   // 32 KB
    __shared__ unsigned short bid16[TILE];     // 16 KB
    __shared__ int cnt[512];                   // hist -> local cursor
    __shared__ int lstart[512];                // exclusive scan (local base)
    __shared__ int gbase[512];                 // reserved global base
    __shared__ int wsum[8];
    int t = threadIdx.x;
    int tile0 = blockIdx.x * TILE;
    int tileE = min(TILE, E - tile0);
    if (t < 512) cnt[t] = 0;
    __syncthreads();
    // load 8 edges/thread (vectorized when full)
    int d[8], s[8];
    int base = t * 8;
    if (base + 8 <= tileE) {
        const int4* d4 = (const int4*)(dst + tile0 + base);
        const int4* s4 = (const int4*)(src + tile0 + base);
        int4 da = d4[0], db = d4[1];
        int4 sa = s4[0], sb = s4[1];
        d[0] = da.x; d[1] = da.y; d[2] = da.z; d[3] = da.w;
        d[4] = db.x; d[5] = db.y; d[6] = db.z; d[7] = db.w;
        s[0] = sa.x; s[1] = sa.y; s[2] = sa.z; s[3] = sa.w;
        s[4] = sb.x; s[5] = sb.y; s[6] = sb.z; s[7] = sb.w;
    } else {
#pragma unroll
        for (int q = 0; q < 8; ++q) {
            int idx = base + q;
            if (idx < tileE) { d[q] = dst[tile0 + idx]; s[q] = src[tile0 + idx]; }
            else d[q] = -1;
        }
    }
#pragma unroll
    for (int q = 0; q < 8; ++q)
        if (d[q] >= 0) atomicAdd(&cnt[d[q] >> BSHIFT], 1);
    __syncthreads();
    // wave-shuffle exclusive scan over cnt[512]: 8 full waves scan 64 each,
    // thread 0 combines wave sums. 4 barriers total.
    int c = 0, ex = 0;
    if (t < 512) {
        c = cnt[t];
        int v = c;
#pragma unroll
        for (int off = 1; off < 64; off <<= 1) {
            int u = __shfl_up(v, off, 64);
            if ((t & 63) >= off) v += u;
        }
        if ((t & 63) == 63) wsum[t >> 6] = v;
        ex = v - c;
    }
    __syncthreads();
    if (t == 0) {
        int run = 0;
#pragma unroll
        for (int w = 0; w < 8; ++w) { int u = wsum[w]; wsum[w] = run; run += u; }
    }
    __syncthreads();
    if (t < 512) {
        ex += wsum[t >> 6];
        gbase[t] = c ? atomicAdd(&bcursor[t], c) : 0;   // reserve global run
        lstart[t] = ex;                                  // local base
        cnt[t] = ex;                                     // local cursor
    }
    __syncthreads();
    // LDS scatter: sort tile's edges by bucket
#pragma unroll
    for (int q = 0; q < 8; ++q) {
        if (d[q] >= 0) {
            int b = d[q] >> BSHIFT;
            int lp = atomicAdd(&cnt[b], 1);
            payload[lp] = ((d[q] & (BUCK - 1)) << 17) | s[q];
            bid16[lp] = (unsigned short)b;
        }
    }
    __syncthreads();
    // coalesced copy-out: consecutive k -> consecutive global addresses
    for (int k = t; k < tileE; k += 1024) {
        int b = bid16[k];
        int ga = gbase[b] + (k - lstart[b]);
        if (ga < (b + 1) * CAP)                          // overflow guard (45 sigma)
            binned[ga] = payload[k];
    }
}

// histogram-only (replaces sortbucket): per-bucket deg -> dinv. No scan, no
// scatter, no csr write.
__global__ __launch_bounds__(1024) void k_hist(const int* __restrict__ bcursor,
                                               const int* __restrict__ binned,
                                               float* __restrict__ dinv, int N) {
    __shared__ int cnt[BUCK];
    int b = blockIdx.x, t = threadIdx.x;
    if (t < BUCK) cnt[t] = 0;
    __syncthreads();
    int beg = b * CAP;
    int end = min(bcursor[b], beg + CAP);
    for (int e0 = beg + 4 * t; e0 < end; e0 += 4096) {
        int4 pk = *(const int4*)&binned[e0];   // 16B-aligned (CAP%4==0)
        int pv[4] = {pk.x, pk.y, pk.z, pk.w};
#pragma unroll
        for (int m = 0; m < 4; ++m)
            if (e0 + m < end) atomicAdd(&cnt[pv[m] >> 17], 1);
    }
    __syncthreads();
    int node = b * BUCK + t;
    if (t < BUCK && node < N)
        dinv[node] = rsqrtf((float)(cnt[t] + 1));   // +1 self loop
}

// ---------------- layer compute ----------------

// hw1h[i,:] = fp16( dinv[i] * (x[i,:] @ W1) ) via MFMA 16x16x32 f16.
__global__ __launch_bounds__(256) void k_gemm1(const float* __restrict__ x,
                                               const float* __restrict__ W1,
                                               const float* __restrict__ dinv,
                                               __half* __restrict__ hw1h, int N) {
    __shared__ _Float16 sX[64 * 136];   // x tile fp16, row pad 136
    __shared__ _Float16 sW[16 * 136];   // W1^T fp16
    __shared__ float    sDi[64];
    __shared__ _Float16 sOut[64 * 16];
    int t = threadIdx.x;
    int row0 = blockIdx.x * 64;
    for (int e = t; e < 2048; e += 256) {
        int n = e & 15, k = e >> 4;
        sW[n * 136 + k] = (_Float16)W1[k * 16 + n];
    }
    const float4* x4 = (const float4*)x;
#pragma unroll
    for (int q = 0; q < 8; ++q) {
        int e = q * 256 + t;
        int r = e >> 5, c4 = e & 31;
        int gr = row0 + r;
        float4 v = (gr < N) ? x4[(size_t)gr * 32 + c4] : make_float4(0.f, 0.f, 0.f, 0.f);
        f16x4 hv = {(_Float16)v.x, (_Float16)v.y, (_Float16)v.z, (_Float16)v.w};
        *(f16x4*)&sX[r * 136 + c4 * 4] = hv;   // one ds_write_b64 (8B-aligned)
    }
    if (t < 64) sDi[t] = (row0 + t < N) ? dinv[row0 + t] : 0.f;
    __syncthreads();
    int w = t >> 6, l = t & 63;
    int m = l & 15, quad = l >> 4;
    f32x4 acc = {0.f, 0.f, 0.f, 0.f};
#pragma unroll
    for (int kc = 0; kc < 4; ++kc) {
        f16x8 a = *(const f16x8*)&sX[(w * 16 + m) * 136 + kc * 32 + quad * 8];
        f16x8 b = *(const f16x8*)&sW[m * 136 + kc * 32 + quad * 8];
        acc = __builtin_amdgcn_mfma_f32_16x16x32_f16(a, b, acc, 0, 0, 0);
    }
#pragma unroll
    for (int r = 0; r < 4; ++r) {
        int nl = w * 16 + quad * 4 + r;
        sOut[nl * 16 + m] = (_Float16)(acc[r] * sDi[nl]);
    }
    __syncthreads();
    int nn = t >> 2, ch = t & 3;
    int gn = row0 + nn;
    if (gn < N)
        *(float2*)&hw1h[(size_t)gn * 16 + ch * 4] = *(float2*)&sOut[nn * 16 + ch * 4];
}

// layer-1 fused: block = bucket. Edge loop over binned[] (dep-free, int4
// index loads), acc[dstLow][17] f32 via ds_add_f32 (stride 17 -> random-dl
// bank spread), then per-node: + self + bias, fused GEMM2 -> hw2h (fp16,
// dinv-prescaled for next layer).
__global__ __launch_bounds__(1024) void k_agg1f(const int* __restrict__ bcursor,
                                                const int* __restrict__ binned,
                                                const float* __restrict__ dinv_g,
                                                const f16x8* __restrict__ hw1v,
                                                const float* __restrict__ W2,
                                                const float* __restrict__ b1,
                                                __half* __restrict__ hw2h, int N) {
    __shared__ float acc[BUCK][17];   // 17.4 KB, pad 17 for banking
    __shared__ float sW[128], sb[16];
    int b = blockIdx.x, t = threadIdx.x;
    if (t < 128) sW[t] = W2[t];
    if (t < 16)  sb[t] = b1[t];
    for (int e = t; e < BUCK * 17; e += 1024) ((float*)acc)[e] = 0.f;
    __syncthreads();
    int beg = b * CAP;
    int end = min(bcursor[b], beg + CAP);
    for (int e0 = beg + 4 * t; e0 < end; e0 += 4096) {
        int4 pk = *(const int4*)&binned[e0];
        int pv[4] = {pk.x, pk.y, pk.z, pk.w};
#pragma unroll
        for (int m = 0; m < 4; ++m) {
            if (e0 + m < end) {
                int dl = pv[m] >> 17, s = pv[m] & 0x1FFFF;
                f16x8 lo = hw1v[2 * (size_t)s];
                f16x8 hi = hw1v[2 * (size_t)s + 1];
                float* ap = acc[dl];
#pragma unroll
                for (int d = 0; d < 8; ++d) {
                    atomicAdd(&ap[d],     (float)lo[d]);
                    atomicAdd(&ap[8 + d], (float)hi[d]);
                }
            }
        }
    }
    __syncthreads();
    if (t < BUCK) {
        int i = b * BUCK + t;
        if (i < N) {
            float di = dinv_g[i];
            f16x8 lo = hw1v[2 * (size_t)i];      // self loop (prescaled row)
            f16x8 hi = hw1v[2 * (size_t)i + 1];
            float h[16];
#pragma unroll
            for (int d = 0; d < 8; ++d) {
                h[d]     = di * (acc[t][d]     + (float)lo[d]) + sb[d];
                h[8 + d] = di * (acc[t][8 + d] + (float)hi[d]) + sb[8 + d];
            }
            float o[8];
#pragma unroll
            for (int d = 0; d < 8; ++d) o[d] = 0.f;
#pragma unroll
            for (int k = 0; k < 16; ++k) {
                float hv = h[k];
#pragma unroll
                for (int d = 0; d < 8; ++d) o[d] += hv * sW[k * 8 + d];
            }
            f16x8 ho;
#pragma unroll
            for (int d = 0; d < 8; ++d) ho[d] = (_Float16)(di * o[d]);
            *(f16x8*)&hw2h[(size_t)i * 8] = ho;
        }
    }
}

// layer-2 fused: block = bucket, acc[dstLow][9], 1 gather/edge, per-node
// bias + Wl dot + sigmoid -> z.
__global__ __launch_bounds__(1024) void k_agg2f(const int* __restrict__ bcursor,
                                                const int* __restrict__ binned,
                                                const float* __restrict__ dinv_g,
                                                const f16x8* __restrict__ hw2v,
                                                const float* __restrict__ Wl,
                                                const float* __restrict__ b2,
                                                const float* __restrict__ bl,
                                                float* __restrict__ z, int N) {
    __shared__ float acc[BUCK][9];    // 9.2 KB
    __shared__ float sW[8], sb[8], sbl;
    int b = blockIdx.x, t = threadIdx.x;
    if (t < 8) { sW[t] = Wl[t]; sb[t] = b2[t]; }
    if (t == 0) sbl = bl[0];
    for (int e = t; e < BUCK * 9; e += 1024) ((float*)acc)[e] = 0.f;
    __syncthreads();
    int beg = b * CAP;
    int end = min(bcursor[b], beg + CAP);
    for (int e0 = beg + 4 * t; e0 < end; e0 += 4096) {
        int4 pk = *(const int4*)&binned[e0];
        int pv[4] = {pk.x, pk.y, pk.z, pk.w};
#pragma unroll
        for (int m = 0; m < 4; ++m) {
            if (e0 + m < end) {
                int dl = pv[m] >> 17, s = pv[m] & 0x1FFFF;
                f16x8 gv = hw2v[(size_t)s];
                float* ap = acc[dl];
#pragma unroll
                for (int d = 0; d < 8; ++d)
                    atomicAdd(&ap[d], (float)gv[d]);
            }
        }
    }
    __syncthreads();
    if (t < BUCK) {
        int i = b * BUCK + t;
        if (i < N) {
            float di = dinv_g[i];
            f16x8 self = hw2v[(size_t)i];
            float v = 0.f;
#pragma unroll
            for (int d = 0; d < 8; ++d) {
                float h = di * (acc[t][d] + (float)self[d]) + sb[d];
                v += h * sW[d];
            }
            z[i] = 1.f / (1.f + __expf(-(v + sbl)));
        }
    }
}

__global__ __launch_bounds__(256) void k_pred(const int2* __restrict__ pe2,
                                              const float* __restrict__ z,
                                              float* __restrict__ out, int P) {
    int p = blockIdx.x * 256 + threadIdx.x;
    if (p < P) {
        int2 e = pe2[p];
        out[p] = z[e.x] * z[e.y];
    }
}

// ---------------- launch ----------------

extern "C" void kernel_launch(void* const* d_in, const int* in_sizes, int n_in,
                              void* d_out, int out_size, void* d_ws, size_t ws_size,
                              hipStream_t stream) {
    const float* x  = (const float*)d_in[0];
    const int*   ei = (const int*)d_in[1];
    const int*   pe = (const int*)d_in[2];
    const float* W1 = (const float*)d_in[3];
    const float* b1 = (const float*)d_in[4];
    const float* W2 = (const float*)d_in[5];
    const float* b2 = (const float*)d_in[6];
    const float* Wl = (const float*)d_in[7];
    const float* bl = (const float*)d_in[8];
    float* out = (float*)d_out;

    const int N = in_sizes[0] / 128;
    const int E = in_sizes[1] / 2;
    const int P = in_sizes[2] / 2;
    const int NBUK = (N + BUCK - 1) >> BSHIFT;   // 391 for N=100000

    const int* src = ei;
    const int* dst = ei + E;

    // workspace (4B words), ~20 MB:
    float*  ws   = (float*)d_ws;
    float*  dinv = ws;                               // N
    __half* hw1h = (__half*)(ws + (size_t)N);        // 16N halves = 8N words (16B-aligned)
    __half* hw2h = (__half*)(ws + (size_t)9 * N);    // 8N halves = 4N words
    float*  z    = ws + (size_t)13 * N;              // N
    int* bcursor = (int*)(ws + (size_t)14 * N);      // NBUK (512 slots)
    int* binned  = bcursor + 512;                    // NBUK*CAP (sparse)

    const int B = 256;

    k_curinit<<<(NBUK + B - 1) / B, B, 0, stream>>>(bcursor, NBUK);
    k_binscatter<<<(E + TILE - 1) / TILE, 1024, 0, stream>>>(src, dst, bcursor, binned, E, NBUK);
    k_hist<<<NBUK, 1024, 0, stream>>>(bcursor, binned, dinv, N);
    k_gemm1<<<(N + 63) / 64, B, 0, stream>>>(x, W1, dinv, hw1h, N);
    k_agg1f<<<NBUK, 1024, 0, stream>>>(bcursor, binned, dinv,
                                       (const f16x8*)hw1h, W2, b1, hw2h, N);
    k_agg2f<<<NBUK, 1024, 0, stream>>>(bcursor, binned, dinv,
                                       (const f16x8*)hw2h, Wl, b2, bl, z, N);
    k_pred<<<(P + B - 1) / B, B, 0, stream>>>((const int2*)pe, z, out, P);
}

// Round 7
// 209.982 us; speedup vs baseline: 3.1255x; 3.1255x over previous
//
#include <hip/hip_runtime.h>
#include <hip/hip_fp16.h>
#include <math.h>

// Fixed-capacity bucketed CSR build (per-tile LDS counting sort -> coalesced
// bucket writes), then node-parallel coalesced gather aggregation with fp16
// gather tables (hw1h 3.2 MB, hw2h 1.6 MB -> fit in one XCD's 4 MB L2).
// gemm1 (x@W1, dinv-prescaled) via MFMA f32_16x16x32_f16.
// R1: wave-shuffle scans. R3: quad-split agg. R5: masked tails + idx prefetch.
// R6 (REVERTED): LDS-atomic aggregation was 8x slower (ds_add ~4cy/lane).
// R7: PADDED CSR — each node's segment rounded up to 16 entries (pads = self
//     index, weight-masked). rowstart 16-aligned -> all agg index loads are
//     int4 (global_load_dwordx4): agg1c requests -25%, agg2c -37%.
#define BSHIFT 8
#define BUCK   256
#define TILE   8192     // edges per scatter workgroup (1024 threads, 8 edges/thread)
#define CAP    12288    // bucket capacity; padded mean ~10.2K, ~22 sigma headroom

typedef _Float16 f16x2 __attribute__((ext_vector_type(2)));
typedef _Float16 f16x4 __attribute__((ext_vector_type(4)));
typedef _Float16 f16x8 __attribute__((ext_vector_type(8)));
typedef float    f32x4 __attribute__((ext_vector_type(4)));

// ---------------- CSR build ----------------

__global__ __launch_bounds__(256) void k_curinit(int* __restrict__ bcursor, int nbuk) {
    int b = blockIdx.x * 256 + threadIdx.x;
    if (b < nbuk) bcursor[b] = b * CAP;
}

// tile scatter with full per-tile LDS counting sort by bucket, so the global
// binned[] writes are lane-consecutive (coalesced bursts per bucket run).
// packed edge = (dst&255)<<17 | src   (src < 2^17)
__global__ __launch_bounds__(1024) void k_binscatter(const int* __restrict__ src,
                                                     const int* __restrict__ dst,
                                                     int* __restrict__ bcursor,
                                                     int* __restrict__ binned, int E, int nbuk) {
    __shared__ int            payload[TILE];   // 32 KB
    __shared__ unsigned short bid16[TILE];     // 16 KB
    __shared__ int cnt[512];                   // hist -> local cursor
    __shared__ int lstart[512];                // exclusive scan (local base)
    __shared__ int gbase[512];                 // reserved global base
    __shared__ int wsum[8];
    int t = threadIdx.x;
    int tile0 = blockIdx.x * TILE;
    int tileE = min(TILE, E - tile0);
    if (t < 512) cnt[t] = 0;
    __syncthreads();
    // load 8 edges/thread (vectorized when full)
    int d[8], s[8];
    int base = t * 8;
    if (base + 8 <= tileE) {
        const int4* d4 = (const int4*)(dst + tile0 + base);
        const int4* s4 = (const int4*)(src + tile0 + base);
        int4 da = d4[0], db = d4[1];
        int4 sa = s4[0], sb = s4[1];
        d[0] = da.x; d[1] = da.y; d[2] = da.z; d[3] = da.w;
        d[4] = db.x; d[5] = db.y; d[6] = db.z; d[7] = db.w;
        s[0] = sa.x; s[1] = sa.y; s[2] = sa.z; s[3] = sa.w;
        s[4] = sb.x; s[5] = sb.y; s[6] = sb.z; s[7] = sb.w;
    } else {
#pragma unroll
        for (int q = 0; q < 8; ++q) {
            int idx = base + q;
            if (idx < tileE) { d[q] = dst[tile0 + idx]; s[q] = src[tile0 + idx]; }
            else d[q] = -1;
        }
    }
#pragma unroll
    for (int q = 0; q < 8; ++q)
        if (d[q] >= 0) atomicAdd(&cnt[d[q] >> BSHIFT], 1);
    __syncthreads();
    // wave-shuffle exclusive scan over cnt[512]: 8 full waves scan 64 each,
    // thread 0 combines wave sums. 4 barriers total.
    int c = 0, ex = 0;
    if (t < 512) {
        c = cnt[t];
        int v = c;
#pragma unroll
        for (int off = 1; off < 64; off <<= 1) {
            int u = __shfl_up(v, off, 64);
            if ((t & 63) >= off) v += u;
        }
        if ((t & 63) == 63) wsum[t >> 6] = v;
        ex = v - c;
    }
    __syncthreads();
    if (t == 0) {
        int run = 0;
#pragma unroll
        for (int w = 0; w < 8; ++w) { int u = wsum[w]; wsum[w] = run; run += u; }
    }
    __syncthreads();
    if (t < 512) {
        ex += wsum[t >> 6];
        gbase[t] = c ? atomicAdd(&bcursor[t], c) : 0;   // reserve global run
        lstart[t] = ex;                                  // local base
        cnt[t] = ex;                                     // local cursor
    }
    __syncthreads();
    // LDS scatter: sort tile's edges by bucket
#pragma unroll
    for (int q = 0; q < 8; ++q) {
        if (d[q] >= 0) {
            int b = d[q] >> BSHIFT;
            int lp = atomicAdd(&cnt[b], 1);
            payload[lp] = ((d[q] & (BUCK - 1)) << 17) | s[q];
            bid16[lp] = (unsigned short)b;
        }
    }
    __syncthreads();
    // coalesced copy-out: consecutive k -> consecutive global addresses
    for (int k = t; k < tileE; k += 1024) {
        int b = bid16[k];
        int ga = gbase[b] + (k - lstart[b]);
        if (ga < (b + 1) * CAP)                          // overflow guard
            binned[ga] = payload[k];
    }
}

// per-bucket counting sort -> csr_src (dst-sorted, PADDED-to-16 segments),
// rowstart/rowend, dinv. Pad slots filled with the node's own index (valid,
// hot, weight-masked by agg kernels via c < rowend).
__global__ __launch_bounds__(1024) void k_sortbucket(const int* __restrict__ bcursor,
                                                     const int* __restrict__ binned,
                                                     int* __restrict__ csr_src,
                                                     int* __restrict__ rowstart,
                                                     int* __restrict__ rowend,
                                                     float* __restrict__ dinv, int N) {
    __shared__ int cnt[BUCK];
    __shared__ int cur[BUCK];
    __shared__ int wsum[4];
    int b = blockIdx.x, t = threadIdx.x;
    if (t < BUCK) cnt[t] = 0;
    __syncthreads();
    int beg = b * CAP;
    int end = min(bcursor[b], beg + CAP);
    int v[12];
#pragma unroll
    for (int q = 0; q < 12; ++q) {
        int e = beg + q * 1024 + t;
        v[q] = (e < end) ? binned[e] : -1;
    }
#pragma unroll
    for (int q = 0; q < 12; ++q)
        if (v[q] >= 0) atomicAdd(&cnt[v[q] >> 17], 1);
    __syncthreads();
    // wave-shuffle exclusive scan over PADDED counts (4 full waves + combine)
    int c = 0, p = 0, ex = 0;
    if (t < BUCK) {
        c = cnt[t];
        p = (c + 15) & ~15;          // pad each segment to a multiple of 16
        int s = p;
#pragma unroll
        for (int off = 1; off < 64; off <<= 1) {
            int u = __shfl_up(s, off, 64);
            if ((t & 63) >= off) s += u;
        }
        if ((t & 63) == 63) wsum[t >> 6] = s;
        ex = s - p;
    }
    __syncthreads();
    if (t == 0) {
        int run = 0;
#pragma unroll
        for (int w = 0; w < 4; ++w) { int u = wsum[w]; wsum[w] = run; run += u; }
    }
    __syncthreads();
    if (t < BUCK) {
        ex += wsum[t >> 6];
        cur[t] = ex;
        int node = b * BUCK + t;
        if (node < N) {
            rowstart[node] = beg + ex;           // 16-aligned local offset
            rowend[node]   = beg + ex + c;
            dinv[node] = rsqrtf((float)(c + 1)); // +1 self loop
            // fill pad slots with self index (safe gather target, masked out)
            for (int pp = c; pp < p && ex + pp < CAP; ++pp)
                csr_src[beg + ex + pp] = node;
        }
    }
    __syncthreads();
#pragma unroll
    for (int q = 0; q < 12; ++q) {
        if (v[q] >= 0) {
            int pos = atomicAdd(&cur[v[q] >> 17], 1);
            if (pos < CAP) csr_src[beg + pos] = v[q] & 0x1FFFF;
        }
    }
}

// ---------------- layer compute ----------------

// hw1h[i,:] = fp16( dinv[i] * (x[i,:] @ W1) ) via MFMA 16x16x32 f16.
__global__ __launch_bounds__(256) void k_gemm1(const float* __restrict__ x,
                                               const float* __restrict__ W1,
                                               const float* __restrict__ dinv,
                                               __half* __restrict__ hw1h, int N) {
    __shared__ _Float16 sX[64 * 136];   // x tile fp16, row pad 136
    __shared__ _Float16 sW[16 * 136];   // W1^T fp16
    __shared__ float    sDi[64];
    __shared__ _Float16 sOut[64 * 16];
    int t = threadIdx.x;
    int row0 = blockIdx.x * 64;
    for (int e = t; e < 2048; e += 256) {
        int n = e & 15, k = e >> 4;
        sW[n * 136 + k] = (_Float16)W1[k * 16 + n];
    }
    const float4* x4 = (const float4*)x;
#pragma unroll
    for (int q = 0; q < 8; ++q) {
        int e = q * 256 + t;
        int r = e >> 5, c4 = e & 31;
        int gr = row0 + r;
        float4 v = (gr < N) ? x4[(size_t)gr * 32 + c4] : make_float4(0.f, 0.f, 0.f, 0.f);
        f16x4 hv = {(_Float16)v.x, (_Float16)v.y, (_Float16)v.z, (_Float16)v.w};
        *(f16x4*)&sX[r * 136 + c4 * 4] = hv;   // one ds_write_b64 (8B-aligned)
    }
    if (t < 64) sDi[t] = (row0 + t < N) ? dinv[row0 + t] : 0.f;
    __syncthreads();
    int w = t >> 6, l = t & 63;
    int m = l & 15, quad = l >> 4;
    f32x4 acc = {0.f, 0.f, 0.f, 0.f};
#pragma unroll
    for (int kc = 0; kc < 4; ++kc) {
        f16x8 a = *(const f16x8*)&sX[(w * 16 + m) * 136 + kc * 32 + quad * 8];
        f16x8 b = *(const f16x8*)&sW[m * 136 + kc * 32 + quad * 8];
        acc = __builtin_amdgcn_mfma_f32_16x16x32_f16(a, b, acc, 0, 0, 0);
    }
#pragma unroll
    for (int r = 0; r < 4; ++r) {
        int nl = w * 16 + quad * 4 + r;
        sOut[nl * 16 + m] = (_Float16)(acc[r] * sDi[nl]);
    }
    __syncthreads();
    int nn = t >> 2, ch = t & 3;
    int gn = row0 + nn;
    if (gn < N)
        *(float2*)&hw1h[(size_t)gn * 16 + ch * 4] = *(float2*)&sOut[nn * 16 + ch * 4];
}

// layer-1: 4 lanes/node, quad-split edge list, int4 index loads (16-aligned
// padded segments), 2-deep index prefetch, masked full-width final chunk,
// shfl_xor butterfly merge, fused register GEMM2 (lane j -> out dims 2j,2j+1)
// -> hw2h (fp16, dinv-prescaled).
__global__ __launch_bounds__(256) void k_agg1c(const int* __restrict__ rowstart,
                                               const int* __restrict__ rowend,
                                               const int* __restrict__ csr_src,
                                               const f16x8* __restrict__ hw1v,
                                               const float* __restrict__ W2,
                                               const float* __restrict__ b1,
                                               __half* __restrict__ hw2h, int N) {
    __shared__ float sW[128], sb[16];
    int t = threadIdx.x;
    if (t < 128) sW[t] = W2[t];
    if (t < 16)  sb[t] = b1[t];
    __syncthreads();
    int q = t >> 2, j = t & 3;
    int i = blockIdx.x * 64 + q;
    if (i >= N) return;
    int beg = rowstart[i], end = rowend[i];
    int deg = end - beg;
    float di = rsqrtf((float)(deg + 1));
    float a[16];
#pragma unroll
    for (int d = 0; d < 16; ++d) a[d] = 0.f;
    int nfull = deg >> 4;
    int base0 = beg + 4 * j;                   // beg 16-aligned -> int4-safe
    int4 s4;
    if (nfull > 0) s4 = *(const int4*)&csr_src[base0];
    for (int ch = 0; ch < nfull; ++ch) {
        int sv[4] = {s4.x, s4.y, s4.z, s4.w};
        f16x8 lo[4], hi[4];
#pragma unroll
        for (int m = 0; m < 4; ++m) {
            lo[m] = hw1v[2 * (size_t)sv[m]];
            hi[m] = hw1v[2 * (size_t)sv[m] + 1];
        }
        int4 sn;
        if (ch + 1 < nfull)                    // prefetch next chunk's indices
            sn = *(const int4*)&csr_src[base0 + (ch + 1) * 16];
#pragma unroll
        for (int m = 0; m < 4; ++m) {
#pragma unroll
            for (int d = 0; d < 8; ++d) {
                a[d]     += (float)lo[m][d];
                a[8 + d] += (float)hi[m][d];
            }
        }
        if (ch + 1 < nfull) s4 = sn;
    }
    if (deg & 15) {                            // masked full-width final chunk
        int cb = base0 + nfull * 16;
        int4 st = *(const int4*)&csr_src[cb];  // pads initialized = self idx
        int   sr[4] = {st.x, st.y, st.z, st.w};
        f16x8 lo[4], hi[4];
#pragma unroll
        for (int m = 0; m < 4; ++m) {
            lo[m] = hw1v[2 * (size_t)sr[m]];
            hi[m] = hw1v[2 * (size_t)sr[m] + 1];
        }
#pragma unroll
        for (int m = 0; m < 4; ++m) {
            float wr = (cb + m < end) ? 1.f : 0.f;
#pragma unroll
            for (int d = 0; d < 8; ++d) {
                a[d]     += wr * (float)lo[m][d];
                a[8 + d] += wr * (float)hi[m][d];
            }
        }
    }
    if (j == 0) {   // self loop (once per node)
        f16x8 lo = hw1v[2 * (size_t)i];
        f16x8 hi = hw1v[2 * (size_t)i + 1];
#pragma unroll
        for (int d = 0; d < 8; ++d) {
            a[d]     += (float)lo[d];
            a[8 + d] += (float)hi[d];
        }
    }
    // butterfly merge across the quad
#pragma unroll
    for (int d = 0; d < 16; ++d) a[d] += __shfl_xor(a[d], 1, 4);
#pragma unroll
    for (int d = 0; d < 16; ++d) a[d] += __shfl_xor(a[d], 2, 4);
    // fused GEMM2: lane j computes output dims 2j, 2j+1
    float o0 = 0.f, o1 = 0.f;
#pragma unroll
    for (int k = 0; k < 16; ++k) {
        float hv = di * a[k] + sb[k];
        o0 += hv * sW[k * 8 + 2 * j];
        o1 += hv * sW[k * 8 + 2 * j + 1];
    }
    f16x2 ho = {(_Float16)(di * o0), (_Float16)(di * o1)};
    *(f16x2*)&hw2h[(size_t)i * 8 + 2 * j] = ho;   // 4B store, 16B/node across quad
}

// layer-2: 4 lanes/node, 8-dim accumulator, int4 index loads + prefetch +
// masked final chunk, butterfly merge, Wl dot + sigmoid.
__global__ __launch_bounds__(256) void k_agg2c(const int* __restrict__ rowstart,
                                               const int* __restrict__ rowend,
                                               const int* __restrict__ csr_src,
                                               const f16x8* __restrict__ hw2v,
                                               const float* __restrict__ Wl,
                                               const float* __restrict__ b2,
                                               const float* __restrict__ bl,
                                               float* __restrict__ z, int N) {
    __shared__ float sW[8], sb[8], sbl;
    int t = threadIdx.x;
    if (t < 8) { sW[t] = Wl[t]; sb[t] = b2[t]; }
    if (t == 0) sbl = bl[0];
    __syncthreads();
    int q = t >> 2, j = t & 3;
    int i = blockIdx.x * 64 + q;
    if (i >= N) return;
    int beg = rowstart[i], end = rowend[i];
    int deg = end - beg;
    float di = rsqrtf((float)(deg + 1));
    float a[8];
#pragma unroll
    for (int d = 0; d < 8; ++d) a[d] = 0.f;
    int nfull = deg >> 4;
    int base0 = beg + 4 * j;
    int4 s4;
    if (nfull > 0) s4 = *(const int4*)&csr_src[base0];
    for (int ch = 0; ch < nfull; ++ch) {
        int sv[4] = {s4.x, s4.y, s4.z, s4.w};
        f16x8 gv[4];
#pragma unroll
        for (int m = 0; m < 4; ++m) gv[m] = hw2v[(size_t)sv[m]];
        int4 sn;
        if (ch + 1 < nfull)
            sn = *(const int4*)&csr_src[base0 + (ch + 1) * 16];
#pragma unroll
        for (int m = 0; m < 4; ++m)
#pragma unroll
            for (int d = 0; d < 8; ++d) a[d] += (float)gv[m][d];
        if (ch + 1 < nfull) s4 = sn;
    }
    if (deg & 15) {
        int cb = base0 + nfull * 16;
        int4 st = *(const int4*)&csr_src[cb];
        int sr[4] = {st.x, st.y, st.z, st.w};
        f16x8 gv[4];
#pragma unroll
        for (int m = 0; m < 4; ++m) gv[m] = hw2v[(size_t)sr[m]];
#pragma unroll
        for (int m = 0; m < 4; ++m) {
            float wr = (cb + m < end) ? 1.f : 0.f;
#pragma unroll
            for (int d = 0; d < 8; ++d) a[d] += wr * (float)gv[m][d];
        }
    }
    if (j == 0) {
        f16x8 self = hw2v[(size_t)i];
#pragma unroll
        for (int d = 0; d < 8; ++d) a[d] += (float)self[d];
    }
#pragma unroll
    for (int d = 0; d < 8; ++d) a[d] += __shfl_xor(a[d], 1, 4);
#pragma unroll
    for (int d = 0; d < 8; ++d) a[d] += __shfl_xor(a[d], 2, 4);
    if (j == 0) {
        float v = 0.f;
#pragma unroll
        for (int d = 0; d < 8; ++d) {
            float h = di * a[d] + sb[d];
            v += h * sW[d];
        }
        z[i] = 1.f / (1.f + __expf(-(v + sbl)));
    }
}

__global__ __launch_bounds__(256) void k_pred(const int2* __restrict__ pe2,
                                              const float* __restrict__ z,
                                              float* __restrict__ out, int P) {
    int p = blockIdx.x * 256 + threadIdx.x;
    if (p < P) {
        int2 e = pe2[p];
        out[p] = z[e.x] * z[e.y];
    }
}

// ---------------- launch ----------------

extern "C" void kernel_launch(void* const* d_in, const int* in_sizes, int n_in,
                              void* d_out, int out_size, void* d_ws, size_t ws_size,
                              hipStream_t stream) {
    const float* x  = (const float*)d_in[0];
    const int*   ei = (const int*)d_in[1];
    const int*   pe = (const int*)d_in[2];
    const float* W1 = (const float*)d_in[3];
    const float* b1 = (const float*)d_in[4];
    const float* W2 = (const float*)d_in[5];
    const float* b2 = (const float*)d_in[6];
    const float* Wl = (const float*)d_in[7];
    const float* bl = (const float*)d_in[8];
    float* out = (float*)d_out;

    const int N = in_sizes[0] / 128;
    const int E = in_sizes[1] / 2;
    const int P = in_sizes[2] / 2;
    const int NBUK = (N + BUCK - 1) >> BSHIFT;   // 391 for N=100000

    const int* src = ei;
    const int* dst = ei + E;

    // workspace (4B words), ~45 MB:
    float*  ws   = (float*)d_ws;
    float*  dinv = ws;                               // N
    __half* hw1h = (__half*)(ws + (size_t)N);        // 16N halves = 8N words (16B-aligned)
    __half* hw2h = (__half*)(ws + (size_t)9 * N);    // 8N halves = 4N words
    float*  z    = ws + (size_t)13 * N;              // N
    int* rowstart = (int*)(ws + (size_t)14 * N);     // N
    int* rowend   = rowstart + N;                    // N
    int* bcursor  = rowend + N;                      // NBUK
    int* binned   = bcursor + 512;                   // NBUK*CAP (sparse)
    int* csr_src  = binned + (size_t)NBUK * CAP;     // NBUK*CAP (sparse, padded segs)

    const int B = 256;

    k_curinit<<<(NBUK + B - 1) / B, B, 0, stream>>>(bcursor, NBUK);
    k_binscatter<<<(E + TILE - 1) / TILE, 1024, 0, stream>>>(src, dst, bcursor, binned, E, NBUK);
    k_sortbucket<<<NBUK, 1024, 0, stream>>>(bcursor, binned, csr_src, rowstart, rowend, dinv, N);
    k_gemm1<<<(N + 63) / 64, B, 0, stream>>>(x, W1, dinv, hw1h, N);
    k_agg1c<<<(N + 63) / 64, B, 0, stream>>>(rowstart, rowend, csr_src,
                                             (const f16x8*)hw1h, W2, b1, hw2h, N);
    k_agg2c<<<(N + 63) / 64, B, 0, stream>>>(rowstart, rowend, csr_src,
                                             (const f16x8*)hw2h, Wl, b2, bl, z, N);
    k_pred<<<(P + B - 1) / B, B, 0, stream>>>((const int2*)pe, z, out, P);
}

// Round 8
// 209.438 us; speedup vs baseline: 3.1337x; 1.0026x over previous
//
#include <hip/hip_runtime.h>
#include <hip/hip_fp16.h>
#include <math.h>

// Fixed-capacity bucketed CSR build (per-tile LDS counting sort -> coalesced
// bucket writes), then node-parallel coalesced gather aggregation with fp16
// gather tables (hw1h 3.2 MB, hw2h 1.6 MB -> L2-resident).
// gemm1 (x@W1, dinv-prescaled) via MFMA f32_16x16x32_f16.
// R1: wave-shuffle scans. R3: quad-split agg. R5: masked tails + idx prefetch.
// R6 (REVERTED): LDS-atomic aggregation 8x slower. R7: padded-to-16 CSR
// segments -> int4 index loads (neutral, kept for alignment).
// R8: hybrid lane map in agg kernels — quad = (j2 feature-half, j4 edge
//     subgroup). Lane pairs share each gathered row's cache line (distinct
//     lines per gather instr halved), per-lane VALU halved in agg1, and
//     chunks unrolled 2-deep (16 gathers in flight).
#define BSHIFT 8
#define BUCK   256
#define TILE   8192     // edges per scatter workgroup (1024 threads, 8 edges/thread)
#define CAP    12288    // bucket capacity; padded mean ~10.2K, ~22 sigma headroom

typedef _Float16 f16x2 __attribute__((ext_vector_type(2)));
typedef _Float16 f16x4 __attribute__((ext_vector_type(4)));
typedef _Float16 f16x8 __attribute__((ext_vector_type(8)));
typedef float    f32x4 __attribute__((ext_vector_type(4)));

// ---------------- CSR build ----------------

__global__ __launch_bounds__(256) void k_curinit(int* __restrict__ bcursor, int nbuk) {
    int b = blockIdx.x * 256 + threadIdx.x;
    if (b < nbuk) bcursor[b] = b * CAP;
}

// tile scatter with full per-tile LDS counting sort by bucket, so the global
// binned[] writes are lane-consecutive (coalesced bursts per bucket run).
// packed edge = (dst&255)<<17 | src   (src < 2^17)
__global__ __launch_bounds__(1024) void k_binscatter(const int* __restrict__ src,
                                                     const int* __restrict__ dst,
                                                     int* __restrict__ bcursor,
                                                     int* __restrict__ binned, int E, int nbuk) {
    __shared__ int            payload[TILE];   // 32 KB
    __shared__ unsigned short bid16[TILE];     // 16 KB
    __shared__ int cnt[512];                   // hist -> local cursor
    __shared__ int lstart[512];                // exclusive scan (local base)
    __shared__ int gbase[512];                 // reserved global base
    __shared__ int wsum[8];
    int t = threadIdx.x;
    int tile0 = blockIdx.x * TILE;
    int tileE = min(TILE, E - tile0);
    if (t < 512) cnt[t] = 0;
    __syncthreads();
    // load 8 edges/thread (vectorized when full)
    int d[8], s[8];
    int base = t * 8;
    if (base + 8 <= tileE) {
        const int4* d4 = (const int4*)(dst + tile0 + base);
        const int4* s4 = (const int4*)(src + tile0 + base);
        int4 da = d4[0], db = d4[1];
        int4 sa = s4[0], sb = s4[1];
        d[0] = da.x; d[1] = da.y; d[2] = da.z; d[3] = da.w;
        d[4] = db.x; d[5] = db.y; d[6] = db.z; d[7] = db.w;
        s[0] = sa.x; s[1] = sa.y; s[2] = sa.z; s[3] = sa.w;
        s[4] = sb.x; s[5] = sb.y; s[6] = sb.z; s[7] = sb.w;
    } else {
#pragma unroll
        for (int q = 0; q < 8; ++q) {
            int idx = base + q;
            if (idx < tileE) { d[q] = dst[tile0 + idx]; s[q] = src[tile0 + idx]; }
            else d[q] = -1;
        }
    }
#pragma unroll
    for (int q = 0; q < 8; ++q)
        if (d[q] >= 0) atomicAdd(&cnt[d[q] >> BSHIFT], 1);
    __syncthreads();
    // wave-shuffle exclusive scan over cnt[512]: 8 full waves scan 64 each,
    // thread 0 combines wave sums. 4 barriers total.
    int c = 0, ex = 0;
    if (t < 512) {
        c = cnt[t];
        int v = c;
#pragma unroll
        for (int off = 1; off < 64; off <<= 1) {
            int u = __shfl_up(v, off, 64);
            if ((t & 63) >= off) v += u;
        }
        if ((t & 63) == 63) wsum[t >> 6] = v;
        ex = v - c;
    }
    __syncthreads();
    if (t == 0) {
        int run = 0;
#pragma unroll
        for (int w = 0; w < 8; ++w) { int u = wsum[w]; wsum[w] = run; run += u; }
    }
    __syncthreads();
    if (t < 512) {
        ex += wsum[t >> 6];
        gbase[t] = c ? atomicAdd(&bcursor[t], c) : 0;   // reserve global run
        lstart[t] = ex;                                  // local base
        cnt[t] = ex;                                     // local cursor
    }
    __syncthreads();
    // LDS scatter: sort tile's edges by bucket
#pragma unroll
    for (int q = 0; q < 8; ++q) {
        if (d[q] >= 0) {
            int b = d[q] >> BSHIFT;
            int lp = atomicAdd(&cnt[b], 1);
            payload[lp] = ((d[q] & (BUCK - 1)) << 17) | s[q];
            bid16[lp] = (unsigned short)b;
        }
    }
    __syncthreads();
    // coalesced copy-out: consecutive k -> consecutive global addresses
    for (int k = t; k < tileE; k += 1024) {
        int b = bid16[k];
        int ga = gbase[b] + (k - lstart[b]);
        if (ga < (b + 1) * CAP)                          // overflow guard
            binned[ga] = payload[k];
    }
}

// per-bucket counting sort -> csr_src (dst-sorted, PADDED-to-16 segments),
// rowstart/rowend, dinv. Pad slots filled with the node's own index (valid,
// hot, weight-masked by agg kernels).
__global__ __launch_bounds__(1024) void k_sortbucket(const int* __restrict__ bcursor,
                                                     const int* __restrict__ binned,
                                                     int* __restrict__ csr_src,
                                                     int* __restrict__ rowstart,
                                                     int* __restrict__ rowend,
                                                     float* __restrict__ dinv, int N) {
    __shared__ int cnt[BUCK];
    __shared__ int cur[BUCK];
    __shared__ int wsum[4];
    int b = blockIdx.x, t = threadIdx.x;
    if (t < BUCK) cnt[t] = 0;
    __syncthreads();
    int beg = b * CAP;
    int end = min(bcursor[b], beg + CAP);
    int v[12];
#pragma unroll
    for (int q = 0; q < 12; ++q) {
        int e = beg + q * 1024 + t;
        v[q] = (e < end) ? binned[e] : -1;
    }
#pragma unroll
    for (int q = 0; q < 12; ++q)
        if (v[q] >= 0) atomicAdd(&cnt[v[q] >> 17], 1);
    __syncthreads();
    // wave-shuffle exclusive scan over PADDED counts (4 full waves + combine)
    int c = 0, p = 0, ex = 0;
    if (t < BUCK) {
        c = cnt[t];
        p = (c + 15) & ~15;          // pad each segment to a multiple of 16
        int s = p;
#pragma unroll
        for (int off = 1; off < 64; off <<= 1) {
            int u = __shfl_up(s, off, 64);
            if ((t & 63) >= off) s += u;
        }
        if ((t & 63) == 63) wsum[t >> 6] = s;
        ex = s - p;
    }
    __syncthreads();
    if (t == 0) {
        int run = 0;
#pragma unroll
        for (int w = 0; w < 4; ++w) { int u = wsum[w]; wsum[w] = run; run += u; }
    }
    __syncthreads();
    if (t < BUCK) {
        ex += wsum[t >> 6];
        cur[t] = ex;
        int node = b * BUCK + t;
        if (node < N) {
            rowstart[node] = beg + ex;           // 16-aligned local offset
            rowend[node]   = beg + ex + c;
            dinv[node] = rsqrtf((float)(c + 1)); // +1 self loop
            // fill pad slots with self index (safe gather target, masked out)
            for (int pp = c; pp < p && ex + pp < CAP; ++pp)
                csr_src[beg + ex + pp] = node;
        }
    }
    __syncthreads();
#pragma unroll
    for (int q = 0; q < 12; ++q) {
        if (v[q] >= 0) {
            int pos = atomicAdd(&cur[v[q] >> 17], 1);
            if (pos < CAP) csr_src[beg + pos] = v[q] & 0x1FFFF;
        }
    }
}

// ---------------- layer compute ----------------

// hw1h[i,:] = fp16( dinv[i] * (x[i,:] @ W1) ) via MFMA 16x16x32 f16.
__global__ __launch_bounds__(256) void k_gemm1(const float* __restrict__ x,
                                               const float* __restrict__ W1,
                                               const float* __restrict__ dinv,
                                               __half* __restrict__ hw1h, int N) {
    __shared__ _Float16 sX[64 * 136];   // x tile fp16, row pad 136
    __shared__ _Float16 sW[16 * 136];   // W1^T fp16
    __shared__ float    sDi[64];
    __shared__ _Float16 sOut[64 * 16];
    int t = threadIdx.x;
    int row0 = blockIdx.x * 64;
    for (int e = t; e < 2048; e += 256) {
        int n = e & 15, k = e >> 4;
        sW[n * 136 + k] = (_Float16)W1[k * 16 + n];
    }
    const float4* x4 = (const float4*)x;
#pragma unroll
    for (int q = 0; q < 8; ++q) {
        int e = q * 256 + t;
        int r = e >> 5, c4 = e & 31;
        int gr = row0 + r;
        float4 v = (gr < N) ? x4[(size_t)gr * 32 + c4] : make_float4(0.f, 0.f, 0.f, 0.f);
        f16x4 hv = {(_Float16)v.x, (_Float16)v.y, (_Float16)v.z, (_Float16)v.w};
        *(f16x4*)&sX[r * 136 + c4 * 4] = hv;   // one ds_write_b64 (8B-aligned)
    }
    if (t < 64) sDi[t] = (row0 + t < N) ? dinv[row0 + t] : 0.f;
    __syncthreads();
    int w = t >> 6, l = t & 63;
    int m = l & 15, quad = l >> 4;
    f32x4 acc = {0.f, 0.f, 0.f, 0.f};
#pragma unroll
    for (int kc = 0; kc < 4; ++kc) {
        f16x8 a = *(const f16x8*)&sX[(w * 16 + m) * 136 + kc * 32 + quad * 8];
        f16x8 b = *(const f16x8*)&sW[m * 136 + kc * 32 + quad * 8];
        acc = __builtin_amdgcn_mfma_f32_16x16x32_f16(a, b, acc, 0, 0, 0);
    }
#pragma unroll
    for (int r = 0; r < 4; ++r) {
        int nl = w * 16 + quad * 4 + r;
        sOut[nl * 16 + m] = (_Float16)(acc[r] * sDi[nl]);
    }
    __syncthreads();
    int nn = t >> 2, ch = t & 3;
    int gn = row0 + nn;
    if (gn < N)
        *(float2*)&hw1h[(size_t)gn * 16 + ch * 4] = *(float2*)&sOut[nn * 16 + ch * 4];
}

// layer-1: 4 lanes/node, hybrid map: j2 = feature half (16B of 32B row),
// j4 = edge subgroup. Lane pairs share each row's cache line. Chunks of 8
// edges, unrolled 2-deep (16 gathers in flight). int4 idx loads (16-aligned
// padded segments), masked final chunk, shfl merges, fused register GEMM2
// (lane j -> out dims 2j,2j+1) -> hw2h (fp16, dinv-prescaled).
__global__ __launch_bounds__(256) void k_agg1c(const int* __restrict__ rowstart,
                                               const int* __restrict__ rowend,
                                               const int* __restrict__ csr_src,
                                               const f16x8* __restrict__ hw1v,
                                               const float* __restrict__ W2,
                                               const float* __restrict__ b1,
                                               __half* __restrict__ hw2h, int N) {
    __shared__ float sW[128], sb[16];
    int t = threadIdx.x;
    if (t < 128) sW[t] = W2[t];
    if (t < 16)  sb[t] = b1[t];
    __syncthreads();
    int q = t >> 2, j = t & 3;
    int j2 = j & 1, j4 = j >> 1;
    int i = blockIdx.x * 64 + q;
    if (i >= N) return;
    int beg = rowstart[i], end = rowend[i];
    int deg = end - beg;
    float di = rsqrtf((float)(deg + 1));
    float a[8];
#pragma unroll
    for (int d = 0; d < 8; ++d) a[d] = 0.f;
    int nfull = deg >> 3;                      // 8-edge chunks
    int lbase = beg + 4 * j4;                  // lane's int4 slot (4-aligned)
    int ch = 0;
    for (; ch + 2 <= nfull; ch += 2) {         // 2-deep unroll
        int4 ia = *(const int4*)&csr_src[lbase + 8 * ch];
        int4 ib = *(const int4*)&csr_src[lbase + 8 * (ch + 1)];
        int sa[4] = {ia.x, ia.y, ia.z, ia.w};
        int sc[4] = {ib.x, ib.y, ib.z, ib.w};
        f16x8 ga[4], gb[4];
#pragma unroll
        for (int m = 0; m < 4; ++m) ga[m] = hw1v[2 * (size_t)sa[m] + j2];
#pragma unroll
        for (int m = 0; m < 4; ++m) gb[m] = hw1v[2 * (size_t)sc[m] + j2];
#pragma unroll
        for (int m = 0; m < 4; ++m)
#pragma unroll
            for (int d = 0; d < 8; ++d)
                a[d] += (float)ga[m][d] + (float)gb[m][d];
    }
    if (ch < nfull) {                          // odd leftover full chunk
        int4 ia = *(const int4*)&csr_src[lbase + 8 * ch];
        int sa[4] = {ia.x, ia.y, ia.z, ia.w};
        f16x8 ga[4];
#pragma unroll
        for (int m = 0; m < 4; ++m) ga[m] = hw1v[2 * (size_t)sa[m] + j2];
#pragma unroll
        for (int m = 0; m < 4; ++m)
#pragma unroll
            for (int d = 0; d < 8; ++d) a[d] += (float)ga[m][d];
    }
    if (deg & 7) {                             // masked full-width final chunk
        int cb = lbase + 8 * nfull;            // pads initialized = self idx
        int4 ia = *(const int4*)&csr_src[cb];
        int sa[4] = {ia.x, ia.y, ia.z, ia.w};
        f16x8 ga[4];
#pragma unroll
        for (int m = 0; m < 4; ++m) ga[m] = hw1v[2 * (size_t)sa[m] + j2];
#pragma unroll
        for (int m = 0; m < 4; ++m) {
            float wr = (cb + m < end) ? 1.f : 0.f;
#pragma unroll
            for (int d = 0; d < 8; ++d) a[d] += wr * (float)ga[m][d];
        }
    }
    if (j4 == 0) {                             // self loop: half j2, once
        f16x8 sv = hw1v[2 * (size_t)i + j2];
#pragma unroll
        for (int d = 0; d < 8; ++d) a[d] += (float)sv[d];
    }
    // merge edge subgroups (xor 2): complete half-j2 sums
#pragma unroll
    for (int d = 0; d < 8; ++d) a[d] += __shfl_xor(a[d], 2, 4);
    // other half via xor 1
    float bo[8];
#pragma unroll
    for (int d = 0; d < 8; ++d) bo[d] = __shfl_xor(a[d], 1, 4);
    int oo = 8 * j2, ot = 8 - oo;              // own / other half offsets
    float o0 = 0.f, o1 = 0.f;
#pragma unroll
    for (int d = 0; d < 8; ++d) {
        float hv = di * a[d] + sb[oo + d];
        o0 += hv * sW[(oo + d) * 8 + 2 * j];
        o1 += hv * sW[(oo + d) * 8 + 2 * j + 1];
    }
#pragma unroll
    for (int d = 0; d < 8; ++d) {
        float hv = di * bo[d] + sb[ot + d];
        o0 += hv * sW[(ot + d) * 8 + 2 * j];
        o1 += hv * sW[(ot + d) * 8 + 2 * j + 1];
    }
    f16x2 ho = {(_Float16)(di * o0), (_Float16)(di * o1)};
    *(f16x2*)&hw2h[(size_t)i * 8 + 2 * j] = ho;   // 4B store, 16B/node across quad
}

// layer-2: same hybrid map on 16B rows (j2 = 8B half), chunks of 8, 2-deep
// unroll, masked tail, merges, Wl dot + sigmoid.
__global__ __launch_bounds__(256) void k_agg2c(const int* __restrict__ rowstart,
                                               const int* __restrict__ rowend,
                                               const int* __restrict__ csr_src,
                                               const f16x4* __restrict__ hw2q,
                                               const float* __restrict__ Wl,
                                               const float* __restrict__ b2,
                                               const float* __restrict__ bl,
                                               float* __restrict__ z, int N) {
    __shared__ float sW[8], sb[8], sbl;
    int t = threadIdx.x;
    if (t < 8) { sW[t] = Wl[t]; sb[t] = b2[t]; }
    if (t == 0) sbl = bl[0];
    __syncthreads();
    int q = t >> 2, j = t & 3;
    int j2 = j & 1, j4 = j >> 1;
    int i = blockIdx.x * 64 + q;
    if (i >= N) return;
    int beg = rowstart[i], end = rowend[i];
    int deg = end - beg;
    float di = rsqrtf((float)(deg + 1));
    float a[4];
#pragma unroll
    for (int d = 0; d < 4; ++d) a[d] = 0.f;
    int nfull = deg >> 3;
    int lbase = beg + 4 * j4;
    int ch = 0;
    for (; ch + 2 <= nfull; ch += 2) {
        int4 ia = *(const int4*)&csr_src[lbase + 8 * ch];
        int4 ib = *(const int4*)&csr_src[lbase + 8 * (ch + 1)];
        int sa[4] = {ia.x, ia.y, ia.z, ia.w};
        int sc[4] = {ib.x, ib.y, ib.z, ib.w};
        f16x4 ga[4], gb[4];
#pragma unroll
        for (int m = 0; m < 4; ++m) ga[m] = hw2q[2 * (size_t)sa[m] + j2];
#pragma unroll
        for (int m = 0; m < 4; ++m) gb[m] = hw2q[2 * (size_t)sc[m] + j2];
#pragma unroll
        for (int m = 0; m < 4; ++m)
#pragma unroll
            for (int d = 0; d < 4; ++d)
                a[d] += (float)ga[m][d] + (float)gb[m][d];
    }
    if (ch < nfull) {
        int4 ia = *(const int4*)&csr_src[lbase + 8 * ch];
        int sa[4] = {ia.x, ia.y, ia.z, ia.w};
        f16x4 ga[4];
#pragma unroll
        for (int m = 0; m < 4; ++m) ga[m] = hw2q[2 * (size_t)sa[m] + j2];
#pragma unroll
        for (int m = 0; m < 4; ++m)
#pragma unroll
            for (int d = 0; d < 4; ++d) a[d] += (float)ga[m][d];
    }
    if (deg & 7) {
        int cb = lbase + 8 * nfull;
        int4 ia = *(const int4*)&csr_src[cb];
        int sa[4] = {ia.x, ia.y, ia.z, ia.w};
        f16x4 ga[4];
#pragma unroll
        for (int m = 0; m < 4; ++m) ga[m] = hw2q[2 * (size_t)sa[m] + j2];
#pragma unroll
        for (int m = 0; m < 4; ++m) {
            float wr = (cb + m < end) ? 1.f : 0.f;
#pragma unroll
            for (int d = 0; d < 4; ++d) a[d] += wr * (float)ga[m][d];
        }
    }
    if (j4 == 0) {                             // self loop: half j2, once
        f16x4 sv = hw2q[2 * (size_t)i + j2];
#pragma unroll
        for (int d = 0; d < 4; ++d) a[d] += (float)sv[d];
    }
#pragma unroll
    for (int d = 0; d < 4; ++d) a[d] += __shfl_xor(a[d], 2, 4);
    float bo[4];
#pragma unroll
    for (int d = 0; d < 4; ++d) bo[d] = __shfl_xor(a[d], 1, 4);
    int oo = 4 * j2, ot = 4 - oo;
    float v = 0.f;
#pragma unroll
    for (int d = 0; d < 4; ++d) {
        float h = di * a[d] + sb[oo + d];
        v += h * sW[oo + d];
    }
#pragma unroll
    for (int d = 0; d < 4; ++d) {
        float h = di * bo[d] + sb[ot + d];
        v += h * sW[ot + d];
    }
    if (j == 0)
        z[i] = 1.f / (1.f + __expf(-(v + sbl)));
}

__global__ __launch_bounds__(256) void k_pred(const int2* __restrict__ pe2,
                                              const float* __restrict__ z,
                                              float* __restrict__ out, int P) {
    int p = blockIdx.x * 256 + threadIdx.x;
    if (p < P) {
        int2 e = pe2[p];
        out[p] = z[e.x] * z[e.y];
    }
}

// ---------------- launch ----------------

extern "C" void kernel_launch(void* const* d_in, const int* in_sizes, int n_in,
                              void* d_out, int out_size, void* d_ws, size_t ws_size,
                              hipStream_t stream) {
    const float* x  = (const float*)d_in[0];
    const int*   ei = (const int*)d_in[1];
    const int*   pe = (const int*)d_in[2];
    const float* W1 = (const float*)d_in[3];
    const float* b1 = (const float*)d_in[4];
    const float* W2 = (const float*)d_in[5];
    const float* b2 = (const float*)d_in[6];
    const float* Wl = (const float*)d_in[7];
    const float* bl = (const float*)d_in[8];
    float* out = (float*)d_out;

    const int N = in_sizes[0] / 128;
    const int E = in_sizes[1] / 2;
    const int P = in_sizes[2] / 2;
    const int NBUK = (N + BUCK - 1) >> BSHIFT;   // 391 for N=100000

    const int* src = ei;
    const int* dst = ei + E;

    // workspace (4B words), ~45 MB:
    float*  ws   = (float*)d_ws;
    float*  dinv = ws;                               // N
    __half* hw1h = (__half*)(ws + (size_t)N);        // 16N halves = 8N words (16B-aligned)
    __half* hw2h = (__half*)(ws + (size_t)9 * N);    // 8N halves = 4N words
    float*  z    = ws + (size_t)13 * N;              // N
    int* rowstart = (int*)(ws + (size_t)14 * N);     // N
    int* rowend   = rowstart + N;                    // N
    int* bcursor  = rowend + N;                      // NBUK
    int* binned   = bcursor + 512;                   // NBUK*CAP (sparse)
    int* csr_src  = binned + (size_t)NBUK * CAP;     // NBUK*CAP (sparse, padded segs)

    const int B = 256;

    k_curinit<<<(NBUK + B - 1) / B, B, 0, stream>>>(bcursor, NBUK);
    k_binscatter<<<(E + TILE - 1) / TILE, 1024, 0, stream>>>(src, dst, bcursor, binned, E, NBUK);
    k_sortbucket<<<NBUK, 1024, 0, stream>>>(bcursor, binned, csr_src, rowstart, rowend, dinv, N);
    k_gemm1<<<(N + 63) / 64, B, 0, stream>>>(x, W1, dinv, hw1h, N);
    k_agg1c<<<(N + 63) / 64, B, 0, stream>>>(rowstart, rowend, csr_src,
                                             (const f16x8*)hw1h, W2, b1, hw2h, N);
    k_agg2c<<<(N + 63) / 64, B, 0, stream>>>(rowstart, rowend, csr_src,
                                             (const f16x4*)hw2h, Wl, b2, bl, z, N);
    k_pred<<<(P + B - 1) / B, B, 0, stream>>>((const int2*)pe, z, out, P);
}